// Round 14
// baseline (36.648 us; speedup 1.0000x reference)
//
#include <hip/hip_runtime.h>
#include <hip/hip_fp16.h>

#define G_ 8
#define C_ 64
#define K_ 9
#define H_ 100
#define W_ 160
#define TW_ 16
#define TH_ 8
#define HALO_ 4
#define SW_ (TW_ + 2*HALO_)       // 24 staged cols
#define SH_ (TH_ + 2*HALO_)       // 16 staged rows
#define NREC_ (SW_ * SH_)         // 384 records
#define RECU_ 17                  // 136 B record stride, in u64 units
#define LDSU_ (NREC_ * RECU_)     // 6528 u64 = 52224 B -> 3 blocks/CU

// R13 + two changes: __launch_bounds__(512,4) (VGPR budget 128 instead of the
// 40 the (512,6) build settled at) and phase B restructured so each tap
// ISSUES all 16 u64 LDS loads (4 corners x 32 B) into named locals before
// the 32 hfma2 -- gives the scheduler register room to keep 2-3 taps'
// ds_reads in flight and hide the ~120-cyc LDS latency. All locals
// statically indexed (no scratch spill -- R11/R12 lesson).
__global__ __launch_bounds__(512, 4) void dcn_lds_kernel(
    const float* __restrict__ x,      // [H,W,G*C] f32
    const float* __restrict__ offset, // [H,W,G*K*2]
    const float* __restrict__ mask,   // [H,W,G*K]
    float* __restrict__ out)          // [H,W,G*C]
{
    __shared__ unsigned long long sm[LDSU_];
    const int bid = (int)blockIdx.x;
    const int g   = bid & 7;          // group -> XCD affinity (round-robin)
    const int t   = bid >> 3;         // 0..129 tile id
    const int th  = t / 10, twc = t % 10;
    const int h0  = th * TH_, w0 = twc * TW_;
    const int tid = (int)threadIdx.x;

    const int p   = tid >> 2;           // 0..127 pixel in tile
    const int q   = tid & 3;            // channel quarter (32-B chunk)
    const int chb = q * 16;             // channel base
    const int hh  = h0 + (p >> 4);
    const int ww  = w0 + (p & 15);
    const bool live = (hh < H_);        // ragged bottom tile
    const int pixg = (hh * W_ + ww) * G_ + g;

    // ---- softmax + offset loads hoisted BEFORE barrier ----
    float mv[K_];
    float2 ov[K_];
    if (live) {
        const float* mptr = mask + (size_t)pixg * K_;
        float mmax = -1e30f;
#pragma unroll
        for (int k = 0; k < K_; ++k) { mv[k] = mptr[k]; mmax = fmaxf(mmax, mv[k]); }
        float msum = 0.f;
#pragma unroll
        for (int k = 0; k < K_; ++k) { mv[k] = __expf(mv[k] - mmax); msum += mv[k]; }
        const float minv = 1.f / msum;
#pragma unroll
        for (int k = 0; k < K_; ++k) mv[k] *= minv;

        const float* optr = offset + (size_t)pixg * (K_ * 2);
#pragma unroll
        for (int k = 0; k < K_; ++k) ov[k] = *(const float2*)(optr + 2 * k);
    } else {
#pragma unroll
        for (int k = 0; k < K_; ++k) { mv[k] = 0.f; ov[k] = make_float2(0.f, 0.f); }
    }

    // ---------------- stage x tile (f32 -> f16, swizzled) ----------------
#pragma unroll
    for (int it = 0; it < (NREC_ * 8) / 512; ++it) {
        const int task = it * 512 + tid;
        const int rec = task >> 3, sub = task & 7;   // sub = 8-float chunk
        const int i = rec / SW_, j = rec - i * SW_;
        const int hs = h0 - HALO_ + i, ws = w0 - HALO_ + j;
        if (hs >= 0 && hs < H_ && ws >= 0 && ws < W_) {
            const float* src = x + (size_t)(hs * W_ + ws) * (G_ * C_) + g * C_ + sub * 8;
            const float4 A = *(const float4*)src;
            const float4 B = *(const float4*)(src + 4);
            __half2 p0 = __floats2half2_rn(A.x, A.y);
            __half2 p1 = __floats2half2_rn(A.z, A.w);
            __half2 p2 = __floats2half2_rn(B.x, B.y);
            __half2 p3 = __floats2half2_rn(B.z, B.w);
            const unsigned long long lo =
                ((unsigned long long)*(unsigned*)&p1 << 32) | *(unsigned*)&p0;
            const unsigned long long hi =
                ((unsigned long long)*(unsigned*)&p3 << 32) | *(unsigned*)&p2;
            const int c = sub >> 1, hsel = sub & 1;  // 32-B chunk, 16-B half
            const int base = rec * RECU_ + ((c ^ (rec & 3)) << 2) + hsel * 2;
            sm[base]     = lo;
            sm[base + 1] = hi;
        }
    }
    __syncthreads();

    if (!live) return;

    // ---------------- phase B: loads-first gather + FMA -------------------
    __half2 acc[3][8];
#pragma unroll
    for (int gr = 0; gr < 3; ++gr)
#pragma unroll
        for (int u = 0; u < 8; ++u) acc[gr][u] = __half2(__half(0.f), __half(0.f));

#pragma unroll
    for (int k = 0; k < K_; ++k) {
        const int gr = k / 3;
        const float lh = (float)(hh + k / 3 - 1) + ov[k].x;
        const float lw = (float)(ww + k % 3 - 1) + ov[k].y;
        const float fh0 = floorf(lh), fw0 = floorf(lw);
        const float ft = lh - fh0, gt = lw - fw0;
        const int hI = (int)fh0, wI = (int)fw0;
        const float m = mv[k];

        const float wh0 = (hI >= 0  && hI < H_    ) ? (1.f - ft) * m : 0.f;
        const float wh1 = (hI >= -1 && hI < H_ - 1) ? ft * m         : 0.f;
        const float cw0 = (wI >= 0  && wI < W_    ) ? (1.f - gt)     : 0.f;
        const float cw1 = (wI >= -1 && wI < W_ - 1) ? gt             : 0.f;
        const __half2 W00 = __float2half2_rn(wh0 * cw0);
        const __half2 W01 = __float2half2_rn(wh0 * cw1);
        const __half2 W10 = __float2half2_rn(wh1 * cw0);
        const __half2 W11 = __float2half2_rn(wh1 * cw1);

        const int hc0 = min(max(hI,     0), H_ - 1);
        const int hc1 = min(max(hI + 1, 0), H_ - 1);
        const int wc0 = min(max(wI,     0), W_ - 1);
        const int wc1 = min(max(wI + 1, 0), W_ - 1);

        const bool inbox = (hI >= h0 - HALO_) && (hI <= h0 + TH_ + HALO_ - 2) &&
                           (wI >= w0 - HALO_) && (wI <= w0 + TW_ + HALO_ - 2);

        if (inbox) {
            const int ri0 = hc0 - (h0 - HALO_), ri1 = hc1 - (h0 - HALO_);
            const int rj0 = wc0 - (w0 - HALO_), rj1 = wc1 - (w0 - HALO_);
            const int r00 = ri0 * SW_ + rj0, r01 = ri0 * SW_ + rj1;
            const int r10 = ri1 * SW_ + rj0, r11 = ri1 * SW_ + rj1;

            const int bA = r00 * RECU_ + ((q ^ (r00 & 3)) << 2);
            const int bB = r01 * RECU_ + ((q ^ (r01 & 3)) << 2);
            const int bC = r10 * RECU_ + ((q ^ (r10 & 3)) << 2);
            const int bD = r11 * RECU_ + ((q ^ (r11 & 3)) << 2);

            // issue all 16 loads first (independent -> deep in-flight queue)
            const unsigned long long A0 = sm[bA],     A1 = sm[bA + 1];
            const unsigned long long A2 = sm[bA + 2], A3 = sm[bA + 3];
            const unsigned long long B0 = sm[bB],     B1 = sm[bB + 1];
            const unsigned long long B2 = sm[bB + 2], B3 = sm[bB + 3];
            const unsigned long long C0 = sm[bC],     C1 = sm[bC + 1];
            const unsigned long long C2 = sm[bC + 2], C3 = sm[bC + 3];
            const unsigned long long D0 = sm[bD],     D1 = sm[bD + 1];
            const unsigned long long D2 = sm[bD + 2], D3 = sm[bD + 3];

#define FMA8(Q0, Q1, Q2, Q3, WT)                                              \
            {                                                                 \
                unsigned u32;                                                 \
                u32 = (unsigned)(Q0);         acc[gr][0] = __hfma2(*(__half2*)&u32, (WT), acc[gr][0]); \
                u32 = (unsigned)((Q0) >> 32); acc[gr][1] = __hfma2(*(__half2*)&u32, (WT), acc[gr][1]); \
                u32 = (unsigned)(Q1);         acc[gr][2] = __hfma2(*(__half2*)&u32, (WT), acc[gr][2]); \
                u32 = (unsigned)((Q1) >> 32); acc[gr][3] = __hfma2(*(__half2*)&u32, (WT), acc[gr][3]); \
                u32 = (unsigned)(Q2);         acc[gr][4] = __hfma2(*(__half2*)&u32, (WT), acc[gr][4]); \
                u32 = (unsigned)((Q2) >> 32); acc[gr][5] = __hfma2(*(__half2*)&u32, (WT), acc[gr][5]); \
                u32 = (unsigned)(Q3);         acc[gr][6] = __hfma2(*(__half2*)&u32, (WT), acc[gr][6]); \
                u32 = (unsigned)((Q3) >> 32); acc[gr][7] = __hfma2(*(__half2*)&u32, (WT), acc[gr][7]); \
            }
            FMA8(A0, A1, A2, A3, W00)
            FMA8(B0, B1, B2, B3, W01)
            FMA8(C0, C1, C2, C3, W10)
            FMA8(D0, D1, D2, D3, W11)
#undef FMA8
        } else {
            // rare (P ~5e-4 per tap): direct global f32 loads at clamped coords
#define GCORNER(HC, WC, WT)                                                   \
            {                                                                 \
                const float* s = x + (size_t)((HC) * W_ + (WC)) * (G_ * C_) + g * C_ + chb; \
                _Pragma("unroll")                                             \
                for (int u = 0; u < 4; ++u) {                                 \
                    const float4 v = *(const float4*)(s + u * 4);             \
                    __half2 e0 = __floats2half2_rn(v.x, v.y);                 \
                    __half2 e1 = __floats2half2_rn(v.z, v.w);                 \
                    acc[gr][u*2]   = __hfma2(e0, (WT), acc[gr][u*2]);         \
                    acc[gr][u*2+1] = __hfma2(e1, (WT), acc[gr][u*2+1]);       \
                }                                                             \
            }
            GCORNER(hc0, wc0, W00) GCORNER(hc0, wc1, W01)
            GCORNER(hc1, wc0, W10) GCORNER(hc1, wc1, W11)
#undef GCORNER
        }
    }

    // fold 3 f16 groups in f32, store 16 channels (4x float4, coalesced)
    float* op = out + (size_t)pixg * C_ + chb;
#pragma unroll
    for (int a = 0; a < 8; a += 2) {
        const float2 s0 = __half22float2(acc[0][a]);
        const float2 t1 = __half22float2(acc[1][a]);
        const float2 t2 = __half22float2(acc[2][a]);
        const float2 s1 = __half22float2(acc[0][a + 1]);
        const float2 t3 = __half22float2(acc[1][a + 1]);
        const float2 t4 = __half22float2(acc[2][a + 1]);
        float4 o;
        o.x = s0.x + t1.x + t2.x;
        o.y = s0.y + t1.y + t2.y;
        o.z = s1.x + t3.x + t4.x;
        o.w = s1.y + t3.y + t4.y;
        *(float4*)(op + a * 2) = o;
    }
}

extern "C" void kernel_launch(void* const* d_in, const int* in_sizes, int n_in,
                              void* d_out, int out_size, void* d_ws, size_t ws_size,
                              hipStream_t stream) {
    const float* x      = (const float*)d_in[0];
    const float* offset = (const float*)d_in[1];
    const float* mask   = (const float*)d_in[2];
    float* out          = (float*)d_out;

    // tiles: 13 rows (ceil(100/8)) x 10 cols (160/16) x 8 groups = 1040 blocks
    dcn_lds_kernel<<<1040, 512, 0, stream>>>(x, offset, mask, out);
}